// Round 4
// baseline (363.914 us; speedup 1.0000x reference)
//
#include <hip/hip_runtime.h>
#include <hip/hip_bf16.h>
#include <stdint.h>

#define BB 32768
#define NN 512
#define CHEB_IT 10

typedef __attribute__((ext_vector_type(8))) short bf16x8;
typedef __attribute__((ext_vector_type(4))) float f32x4;

__device__ __forceinline__ void gld_lds16(const void* g, void* l) {
  typedef __attribute__((address_space(1))) const unsigned int gas_u32;
  typedef __attribute__((address_space(3))) unsigned int las_u32;
  __builtin_amdgcn_global_load_lds((gas_u32*)(uintptr_t)g,
                                   (las_u32*)(uint32_t)(uintptr_t)l, 16, 0, 0);
}

__device__ __forceinline__ unsigned short f2bf(float x) {
  __hip_bfloat16 h = __float2bfloat16(x);
  return *reinterpret_cast<unsigned short*>(&h);
}

__device__ __forceinline__ float bf2f(unsigned short u) {
  return __uint_as_float(((unsigned)u) << 16);
}

__device__ __forceinline__ float wave_reduce(float v) {
#pragma unroll
  for (int off = 32; off > 0; off >>= 1) v += __shfl_xor(v, off, 64);
  return v;
}

// Single-block Chebyshev iteration solving Gamma v = SR (1024 threads, no
// inter-block sync). Eigen bounds for Gamma = A A^T/N + I (N=512, MP law):
// [0.97, 5.35]. Full 512x512 bf16 matvec per iteration (L2-resident, 512KB).
// Saad Alg 12.1: x+=p; r-=Ap; rho'=1/(2*sigma1-rho); p=rho'*rho*p+(2rho'/delta)*r.
__device__ void cheb_phase(const unsigned short* __restrict__ Gbf,
                           const float* __restrict__ SR, float* __restrict__ v_out,
                           float* sm) {
  float* sp = sm;         // p vector [512]
  float* apw = sm + 512;  // [8][512] partial combine
  const int t = threadIdx.x;
  const int rg = t >> 7;         // 0..7 row-group (wave-uniform)
  const int c0 = (t & 127) * 4;  // 4 owned columns
  const float theta = 3.16f, delta = 2.19f;
  const float sigma1 = theta / delta;
  float rho = delta / theta;
  float x = 0.f, r = 0.f, p = 0.f;
  if (t < 512) {
    r = SR[t];
    p = r * (1.0f / theta);
  }
  for (int k = 0; k < CHEB_IT; ++k) {
    if (t < 512) sp[t] = p;
    __syncthreads();
    // column-sum matvec via symmetry: a_c = sum_{rows in group} G[row][c]*p[row]
    float a0 = 0, a1 = 0, a2 = 0, a3 = 0;
    for (int j = 0; j < NN; j += 64) {
#pragma unroll
      for (int jj = 0; jj < 8; ++jj) {
        const int row = j + jj * 8 + rg;
        ushort4 u = *(const ushort4*)(Gbf + (size_t)row * NN + c0);
        float pv = sp[row];
        a0 += bf2f(u.x) * pv; a1 += bf2f(u.y) * pv;
        a2 += bf2f(u.z) * pv; a3 += bf2f(u.w) * pv;
      }
    }
    *(float4*)(apw + rg * 512 + c0) = make_float4(a0, a1, a2, a3);
    __syncthreads();
    if (t < 512) {
      float ap = 0.f;
#pragma unroll
      for (int g = 0; g < 8; ++g) ap += apw[g * 512 + t];
      x += p;
      r -= ap;
      const float rho_new = 1.f / (2.f * sigma1 - rho);
      p = rho_new * rho * p + (2.f * rho_new / delta) * r;
      rho = rho_new;
    }
    __syncthreads();  // sp reuse safety
  }
  if (t < 512) v_out[t] = x;
}

// K0: Gamma -> bf16 copy; block 0 zeros colsum[4096]+secsum[64]+v[512].
__global__ __launch_bounds__(256) void k0_prep(
    const float* __restrict__ Gam, unsigned short* __restrict__ Gbf,
    float* __restrict__ small_zero) {
  const int t = threadIdx.x, b = blockIdx.x;
  const size_t base = ((size_t)b * 256 + t) * 8;
  float4 g0 = *(const float4*)(Gam + base);
  float4 g1 = *(const float4*)(Gam + base + 4);
  *(ushort4*)(Gbf + base) = make_ushort4(f2bf(g0.x), f2bf(g0.y), f2bf(g0.z), f2bf(g0.w));
  *(ushort4*)(Gbf + base + 4) = make_ushort4(f2bf(g1.x), f2bf(g1.y), f2bf(g1.z), f2bf(g1.w));
  if (b == 0)
    for (int i = t; i < 4672; i += 256) small_zero[i] = 0.f;
}

// K1: block 0: single-block Chebyshev -> v (hidden under streaming blocks).
//     blocks 1..512: R = exp(sigma-lsh) -> bf16 natural [B][N] (64 rows/block)
//     + colsum buckets. 1024 threads.
__global__ __launch_bounds__(1024) void k1_rexp(
    const float* __restrict__ lsh, const float* __restrict__ sig,
    const float* __restrict__ SR, const unsigned short* __restrict__ Gbf,
    unsigned short* __restrict__ Rb, float* __restrict__ v_out,
    float* __restrict__ colsum) {
  __shared__ __align__(16) float sm[4608];
  if (blockIdx.x == 0) {
    cheb_phase(Gbf, SR, v_out, sm);
    return;
  }
  const int t = threadIdx.x;
  const int wb = blockIdx.x - 1;
  const int g = t >> 7;          // row-group 0..7
  const int c = (t & 127) * 4;   // 4 owned columns
  const size_t base = (size_t)wb * 32768;  // 64 rows x 512
  float c0 = 0.f, c1 = 0.f, c2 = 0.f, c3 = 0.f;
#pragma unroll
  for (int j = 0; j < 8; ++j) {
    const size_t idx = base + (size_t)(g + 8 * j) * 512 + c;
    float4 sv = *(const float4*)(sig + idx);
    float4 lv = *(const float4*)(lsh + idx);
    float r0 = __expf(sv.x - lv.x), r1 = __expf(sv.y - lv.y);
    float r2 = __expf(sv.z - lv.z), r3 = __expf(sv.w - lv.w);
    *(ushort4*)(Rb + idx) = make_ushort4(f2bf(r0), f2bf(r1), f2bf(r2), f2bf(r3));
    c0 += r0; c1 += r1; c2 += r2; c3 += r3;
  }
  float* part = sm;  // [8][512]
  *(float4*)(part + g * 512 + c) = make_float4(c0, c1, c2, c3);
  __syncthreads();
  if (t < 512) {
    float s = 0.f;
#pragma unroll
    for (int gg = 0; gg < 8; ++gg) s += part[gg * 512 + t];
    atomicAdd(&colsum[(wb & 7) * NN + t], s);
  }
}

// K1b: Gp = bf16( diag(v) * Gamma * diag(v) )  (symmetric since Gamma is).
__global__ __launch_bounds__(256) void k1b_gprep(
    const float* __restrict__ Gam, const float* __restrict__ v,
    unsigned short* __restrict__ Gp) {
  const int t = threadIdx.x;
  const size_t e = ((size_t)blockIdx.x * 256 + t) * 8;
  const int i = (int)(e >> 9), j = (int)(e & 511);
  const float vi = v[i];
  float4 va = *(const float4*)(v + j);
  float4 vb = *(const float4*)(v + j + 4);
  float4 g0 = *(const float4*)(Gam + e);
  float4 g1 = *(const float4*)(Gam + e + 4);
  *(ushort4*)(Gp + e) = make_ushort4(f2bf(g0.x * vi * va.x), f2bf(g0.y * vi * va.y),
                                     f2bf(g0.z * vi * va.z), f2bf(g0.w * vi * va.w));
  *(ushort4*)(Gp + e + 4) = make_ushort4(f2bf(g1.x * vi * vb.x), f2bf(g1.y * vi * vb.y),
                                         f2bf(g1.z * vi * vb.z), f2bf(g1.w * vi * vb.w));
}

// K2: GEMM T = R * Gp (BM=256, BN=128, BK=64), fused contraction
//     secsum[bid&63] += sum_{b,n} T[b][n] * R[b][n].
//     8 waves @ 64x64 wave-tile (acc[4][4]) -> 0.5KB LDS-read per MFMA.
//     48KB single-buffer LDS (~3 blocks/CU); same-XCD grouping of the 4
//     n-tiles per b-slice.
__global__ __launch_bounds__(512) void k2_gemm(
    const unsigned short* __restrict__ Rb, const unsigned short* __restrict__ Gp,
    float* __restrict__ secsum) {
  __shared__ __align__(16) unsigned short smem[24576];  // As[256][64] | Bs[128][64]
  const int bid = blockIdx.x;
  const int nt_ = (bid >> 3) & 3;
  const int bs_ = (bid & 7) + ((bid >> 5) << 3);  // 0..127, 4 nt share an XCD slot
  const int b0 = bs_ * 256;
  const int n0 = nt_ * 128;
  const int t = threadIdx.x, lane = t & 63, wv = t >> 6;
  const int wi = (wv >> 1) * 64;  // A row base (4 tiles)
  const int wj = (wv & 1) * 64;   // B col base (2 tiles)
  const int lm = lane & 15, lq = lane >> 4;
  const int xr = lm & 7;
  const int srow = t >> 3, sc = t & 7;
  const int scol = (sc ^ (srow & 7)) * 8;  // pre-swizzled source chunk (involution)
  unsigned short* As = smem;          // [256][64]
  unsigned short* Bs = smem + 16384;  // [128][64]
  f32x4 acc[4][4];
#pragma unroll
  for (int a = 0; a < 4; ++a)
#pragma unroll
    for (int b = 0; b < 4; ++b) acc[a][b] = (f32x4){0.f, 0.f, 0.f, 0.f};

  for (int ch = 0; ch < 8; ++ch) {
    const int kk = ch * 64;
    if (ch) __syncthreads();  // previous compute done before overwrite
#pragma unroll
    for (int ps = 0; ps < 4; ++ps)
      gld_lds16(Rb + (size_t)(b0 + ps * 64 + srow) * NN + kk + scol,
                As + (ps * 64 + srow) * 64 + sc * 8);
#pragma unroll
    for (int ps = 0; ps < 2; ++ps)
      gld_lds16(Gp + (size_t)(n0 + ps * 64 + srow) * NN + kk + scol,
                Bs + (ps * 64 + srow) * 64 + sc * 8);
    __syncthreads();  // implicit vmcnt(0) drain: LDS data visible
#pragma unroll
    for (int s = 0; s < 2; ++s) {
      bf16x8 af[4], bfr[4];
#pragma unroll
      for (int g = 0; g < 4; ++g)
        af[g] = *(const bf16x8*)(As + (wi + g * 16 + lm) * 64 + ((s * 4 + lq) ^ xr) * 8);
#pragma unroll
      for (int g = 0; g < 4; ++g)
        bfr[g] = *(const bf16x8*)(Bs + (wj + g * 16 + lm) * 64 + ((s * 4 + lq) ^ xr) * 8);
#pragma unroll
      for (int gm = 0; gm < 4; ++gm)
#pragma unroll
        for (int gn = 0; gn < 4; ++gn)
          acc[gm][gn] = __builtin_amdgcn_mfma_f32_16x16x32_bf16(af[gm], bfr[gn], acc[gm][gn], 0, 0, 0);
    }
  }
  __syncthreads();

  // epilogue: s = sum_{frag} acc * R[b][n]   (C/D layout: col=lane&15, row=(lane>>4)*4+reg)
  float s_ = 0.f;
#pragma unroll
  for (int gm = 0; gm < 4; ++gm) {
    const int rb = b0 + wi + gm * 16 + lq * 4;
#pragma unroll
    for (int gn = 0; gn < 4; ++gn) {
      const int cl = n0 + wj + gn * 16 + lm;
      const unsigned short* rp = Rb + (size_t)rb * NN + cl;
      s_ += acc[gm][gn][0] * bf2f(rp[0]);
      s_ += acc[gm][gn][1] * bf2f(rp[NN]);
      s_ += acc[gm][gn][2] * bf2f(rp[2 * NN]);
      s_ += acc[gm][gn][3] * bf2f(rp[3 * NN]);
    }
  }
  s_ = wave_reduce(s_);
  float* red = (float*)smem;  // buffers dead
  if (lane == 0) red[wv] = s_;
  __syncthreads();
  if (t == 0) {
    float a = 0;
#pragma unroll
    for (int i = 0; i < 8; ++i) a += red[i];
    atomicAdd(&secsum[bid & 63], a);
  }
}

// K4: loss = -( sum_j (colsum_j/B) v_j SR_j / k - sum(secsum)/(B*2k) )
__global__ __launch_bounds__(512) void k4_final(
    const float* __restrict__ colsum, const float* __restrict__ v,
    const float* __restrict__ SR, const float* __restrict__ secsum,
    const int* __restrict__ kp, float* __restrict__ out) {
  __shared__ float red[8];
  const int t = threadIdx.x;
  float cs = 0;
#pragma unroll
  for (int bk = 0; bk < 8; ++bk) cs += colsum[bk * NN + t];
  float f = (cs * (1.0f / BB)) * v[t] * SR[t];
  f = wave_reduce(f);
  if ((t & 63) == 0) red[t >> 6] = f;
  float h = 0.f;
  if (t < 64) {
    h = secsum[t];
    h = wave_reduce(h);  // wave 0: total of 64 buckets
  }
  __syncthreads();
  if (t == 0) {
    float first = 0;
#pragma unroll
    for (int i = 0; i < 8; ++i) first += red[i];
    float kk = (float)kp[0];
    float sec = h / ((float)BB * 2.0f * kk);
    out[0] = -(first / kk - sec);
  }
}

extern "C" void kernel_launch(void* const* d_in, const int* in_sizes, int n_in,
                              void* d_out, int out_size, void* d_ws, size_t ws_size,
                              hipStream_t stream) {
  const float* lsh = (const float*)d_in[0];
  const float* sig = (const float*)d_in[1];
  const float* SR = (const float*)d_in[2];
  const float* Gam = (const float*)d_in[3];
  const int* kp = (const int*)d_in[4];
  char* ws = (char*)d_ws;
  // layout: colsum 4096f | secsum 64f | v 512f | pad->32KB | Gbf 512KB | Gp 512KB | Rb 32MB
  float* colsum = (float*)ws;
  float* secsum = colsum + 4096;
  float* v = secsum + 64;
  unsigned short* Gbf = (unsigned short*)(ws + (32 << 10));
  unsigned short* Gp = (unsigned short*)(ws + (32 << 10) + (512 << 10));
  unsigned short* Rb = (unsigned short*)(ws + (32 << 10) + (1024 << 10));

  k0_prep<<<128, 256, 0, stream>>>(Gam, Gbf, colsum);
  k1_rexp<<<513, 1024, 0, stream>>>(lsh, sig, SR, Gbf, Rb, v, colsum);
  k1b_gprep<<<128, 256, 0, stream>>>(Gam, v, Gp);
  k2_gemm<<<512, 512, 0, stream>>>(Rb, Gp, secsum);
  k4_final<<<1, 512, 0, stream>>>(colsum, v, SR, secsum, kp, (float*)d_out);
}

// Round 5
// 362.202 us; speedup vs baseline: 1.0047x; 1.0047x over previous
//
#include <hip/hip_runtime.h>
#include <hip/hip_bf16.h>
#include <stdint.h>

#define BB 32768
#define NN 512
#define CHEB_IT 10

typedef __attribute__((ext_vector_type(8))) short bf16x8;
typedef __attribute__((ext_vector_type(4))) float f32x4;

__device__ __forceinline__ void gld_lds16(const void* g, void* l) {
  typedef __attribute__((address_space(1))) const unsigned int gas_u32;
  typedef __attribute__((address_space(3))) unsigned int las_u32;
  __builtin_amdgcn_global_load_lds((gas_u32*)(uintptr_t)g,
                                   (las_u32*)(uint32_t)(uintptr_t)l, 16, 0, 0);
}

__device__ __forceinline__ unsigned short f2bf(float x) {
  __hip_bfloat16 h = __float2bfloat16(x);
  return *reinterpret_cast<unsigned short*>(&h);
}

__device__ __forceinline__ float bf2f(unsigned short u) {
  return __uint_as_float(((unsigned)u) << 16);
}

__device__ __forceinline__ float wave_reduce(float v) {
#pragma unroll
  for (int off = 32; off > 0; off >>= 1) v += __shfl_xor(v, off, 64);
  return v;
}

// Single-block Chebyshev solving Gamma v = SR (1024 threads). Eigen bounds for
// Gamma = A A^T/N + I (N=512, MP law): [0.97, 5.35] -> theta=3.16, delta=2.19
// (constants verified passing in rounds 3-4). Matvec is MLP-batched: 16
// independent global loads issued per group, THEN consumed — avoids the
// serialized load->use chains that made round-4's version ~19us/iter.
__device__ void cheb_phase(const unsigned short* __restrict__ Gbf,
                           const float* __restrict__ SR, float* __restrict__ v_out,
                           float* sm) {
  float* sp = sm;         // p vector [512]
  float* apw = sm + 512;  // [8][512] partial combine
  const int t = threadIdx.x;
  const int rg = t >> 7;         // 0..7 row-group (wave-uniform)
  const int c0 = (t & 127) * 4;  // 4 owned columns
  const float theta = 3.16f, delta = 2.19f;
  const float sigma1 = theta / delta;
  float rho = delta / theta;
  float x = 0.f, r = 0.f, p = 0.f;
  if (t < 512) {
    r = SR[t];
    p = r * (1.0f / theta);
  }
  for (int k = 0; k < CHEB_IT; ++k) {
    if (t < 512) sp[t] = p;
    __syncthreads();
    float a0 = 0, a1 = 0, a2 = 0, a3 = 0;
#pragma unroll
    for (int b = 0; b < 4; ++b) {
      ushort4 u[16];
      float pv[16];
#pragma unroll
      for (int i = 0; i < 16; ++i) {  // 16 independent loads in flight
        const int row = rg + 8 * (b * 16 + i);
        u[i] = *(const ushort4*)(Gbf + (size_t)row * NN + c0);
        pv[i] = sp[row];
      }
#pragma unroll
      for (int i = 0; i < 16; ++i) {
        a0 += bf2f(u[i].x) * pv[i];
        a1 += bf2f(u[i].y) * pv[i];
        a2 += bf2f(u[i].z) * pv[i];
        a3 += bf2f(u[i].w) * pv[i];
      }
    }
    *(float4*)(apw + rg * 512 + c0) = make_float4(a0, a1, a2, a3);
    __syncthreads();
    if (t < 512) {
      float ap = 0.f;
#pragma unroll
      for (int g = 0; g < 8; ++g) ap += apw[g * 512 + t];
      x += p;
      r -= ap;
      const float rho_new = 1.f / (2.f * sigma1 - rho);
      p = rho_new * rho * p + (2.f * rho_new / delta) * r;
      rho = rho_new;
    }
    __syncthreads();  // sp reuse safety
  }
  if (t < 512) v_out[t] = x;
}

// K0: Gamma -> bf16 copy; block 0 zeros colsum[4096]+secsum[64]+v[512].
__global__ __launch_bounds__(256) void k0_prep(
    const float* __restrict__ Gam, unsigned short* __restrict__ Gbf,
    float* __restrict__ small_zero) {
  const int t = threadIdx.x, b = blockIdx.x;
  const size_t base = ((size_t)b * 256 + t) * 8;
  float4 g0 = *(const float4*)(Gam + base);
  float4 g1 = *(const float4*)(Gam + base + 4);
  *(ushort4*)(Gbf + base) = make_ushort4(f2bf(g0.x), f2bf(g0.y), f2bf(g0.z), f2bf(g0.w));
  *(ushort4*)(Gbf + base + 4) = make_ushort4(f2bf(g1.x), f2bf(g1.y), f2bf(g1.z), f2bf(g1.w));
  if (b == 0)
    for (int i = t; i < 4672; i += 256) small_zero[i] = 0.f;
}

// K1: block 0: Chebyshev -> v (hidden under streaming). blocks 1..512:
//     R = exp(sigma-lsh) -> bf16 natural [B][N] (64 rows/block) + colsum.
__global__ __launch_bounds__(1024) void k1_rexp(
    const float* __restrict__ lsh, const float* __restrict__ sig,
    const float* __restrict__ SR, const unsigned short* __restrict__ Gbf,
    unsigned short* __restrict__ Rb, float* __restrict__ v_out,
    float* __restrict__ colsum) {
  __shared__ __align__(16) float sm[4608];
  if (blockIdx.x == 0) {
    cheb_phase(Gbf, SR, v_out, sm);
    return;
  }
  const int t = threadIdx.x;
  const int wb = blockIdx.x - 1;
  const int g = t >> 7;         // row-group 0..7
  const int c = (t & 127) * 4;  // 4 owned columns
  const size_t base = (size_t)wb * 32768;  // 64 rows x 512
  float c0 = 0.f, c1 = 0.f, c2 = 0.f, c3 = 0.f;
#pragma unroll
  for (int j = 0; j < 8; ++j) {
    const size_t idx = base + (size_t)(g + 8 * j) * 512 + c;
    float4 sv = *(const float4*)(sig + idx);
    float4 lv = *(const float4*)(lsh + idx);
    float r0 = __expf(sv.x - lv.x), r1 = __expf(sv.y - lv.y);
    float r2 = __expf(sv.z - lv.z), r3 = __expf(sv.w - lv.w);
    *(ushort4*)(Rb + idx) = make_ushort4(f2bf(r0), f2bf(r1), f2bf(r2), f2bf(r3));
    c0 += r0; c1 += r1; c2 += r2; c3 += r3;
  }
  float* part = sm;  // [8][512]
  *(float4*)(part + g * 512 + c) = make_float4(c0, c1, c2, c3);
  __syncthreads();
  if (t < 512) {
    float s = 0.f;
#pragma unroll
    for (int gg = 0; gg < 8; ++gg) s += part[gg * 512 + t];
    atomicAdd(&colsum[(wb & 7) * NN + t], s);
  }
}

// K1b: Gp = bf16( diag(v) * Gamma * diag(v) )  (symmetric since Gamma is).
__global__ __launch_bounds__(256) void k1b_gprep(
    const float* __restrict__ Gam, const float* __restrict__ v,
    unsigned short* __restrict__ Gp) {
  const int t = threadIdx.x;
  const size_t e = ((size_t)blockIdx.x * 256 + t) * 8;
  const int i = (int)(e >> 9), j = (int)(e & 511);
  const float vi = v[i];
  float4 va = *(const float4*)(v + j);
  float4 vb = *(const float4*)(v + j + 4);
  float4 g0 = *(const float4*)(Gam + e);
  float4 g1 = *(const float4*)(Gam + e + 4);
  *(ushort4*)(Gp + e) = make_ushort4(f2bf(g0.x * vi * va.x), f2bf(g0.y * vi * va.y),
                                     f2bf(g0.z * vi * va.z), f2bf(g0.w * vi * va.w));
  *(ushort4*)(Gp + e + 4) = make_ushort4(f2bf(g1.x * vi * vb.x), f2bf(g1.y * vi * vb.y),
                                         f2bf(g1.z * vi * vb.z), f2bf(g1.w * vi * vb.w));
}

// K2: GEMM T = R * Gp (128x128 tile, K=512), fused contraction
//     secsum[bid&63] += sum_{b,n} T[b][n] * R[b][n]. Double-buffered LDS,
//     issue-early gld_lds, one barrier per chunk. (Round-3 variant verbatim —
//     fastest measured; this round it becomes the top dispatch -> counters.)
__global__ __launch_bounds__(512) void k2_gemm(
    const unsigned short* __restrict__ Rb, const unsigned short* __restrict__ Gp,
    float* __restrict__ secsum) {
  __shared__ __align__(16) unsigned short smem[32768];  // 64KB: 2 x (As 16KB | Bs 16KB)
  const int bid = blockIdx.x;
  const int nt_ = (bid >> 3) & 3;
  const int bs_ = (bid & 7) + ((bid >> 5) << 3);  // 4 n-tiles of a b-slice share an XCD
  const int b0 = bs_ * 128;
  const int n0 = nt_ * 128;
  const int t = threadIdx.x, lane = t & 63, wv = t >> 6;
  const int wi = (wv & 3) * 32, wj = (wv >> 2) * 64;
  const int lm = lane & 15, lq = lane >> 4;
  const int xr = lm & 7;
  const int srow = t >> 3, sc = t & 7;
  const int scol = (sc ^ (srow & 7)) * 8;  // pre-swizzled source chunk (involution)
  f32x4 acc[2][4];
#pragma unroll
  for (int a = 0; a < 2; ++a)
#pragma unroll
    for (int b = 0; b < 4; ++b) acc[a][b] = (f32x4){0.f, 0.f, 0.f, 0.f};

#define STAGE(kk, buf)                                                                   \
  {                                                                                      \
    unsigned short* As_ = smem + (buf)*16384;                                            \
    unsigned short* Bs_ = As_ + 8192;                                                    \
    gld_lds16(Rb + (size_t)(b0 + srow) * NN + (kk) + scol, As_ + srow * 64 + sc * 8);    \
    gld_lds16(Rb + (size_t)(b0 + 64 + srow) * NN + (kk) + scol,                          \
              As_ + (64 + srow) * 64 + sc * 8);                                          \
    gld_lds16(Gp + (size_t)(n0 + srow) * NN + (kk) + scol, Bs_ + srow * 64 + sc * 8);    \
    gld_lds16(Gp + (size_t)(n0 + 64 + srow) * NN + (kk) + scol,                          \
              Bs_ + (64 + srow) * 64 + sc * 8);                                          \
  }

  STAGE(0, 0);
  __syncthreads();
  for (int c = 0; c < 8; ++c) {
    if (c < 7) STAGE((c + 1) * 64, (c + 1) & 1);  // in flight during compute
    const unsigned short* As = smem + (c & 1) * 16384;
    const unsigned short* Bs = As + 8192;
#pragma unroll
    for (int s = 0; s < 2; ++s) {
      bf16x8 af[2], bfr[4];
#pragma unroll
      for (int g = 0; g < 2; ++g)
        af[g] = *(const bf16x8*)(As + (wi + g * 16 + lm) * 64 + ((s * 4 + lq) ^ xr) * 8);
#pragma unroll
      for (int g = 0; g < 4; ++g)
        bfr[g] = *(const bf16x8*)(Bs + (wj + g * 16 + lm) * 64 + ((s * 4 + lq) ^ xr) * 8);
#pragma unroll
      for (int gm = 0; gm < 2; ++gm)
#pragma unroll
        for (int gn = 0; gn < 4; ++gn)
          acc[gm][gn] = __builtin_amdgcn_mfma_f32_16x16x32_bf16(af[gm], bfr[gn], acc[gm][gn], 0, 0, 0);
    }
    __syncthreads();  // drains vmcnt: next buffer ready; cur safe to overwrite
  }
#undef STAGE

  // epilogue: s = sum_{frag} acc * R[b][n]
  float s_ = 0.f;
#pragma unroll
  for (int gm = 0; gm < 2; ++gm) {
    const int rb = b0 + wi + gm * 16 + lq * 4;
#pragma unroll
    for (int gn = 0; gn < 4; ++gn) {
      const int cl = n0 + wj + gn * 16 + lm;
      const unsigned short* rp = Rb + (size_t)rb * NN + cl;
      s_ += acc[gm][gn][0] * bf2f(rp[0]);
      s_ += acc[gm][gn][1] * bf2f(rp[NN]);
      s_ += acc[gm][gn][2] * bf2f(rp[2 * NN]);
      s_ += acc[gm][gn][3] * bf2f(rp[3 * NN]);
    }
  }
  s_ = wave_reduce(s_);
  float* red = (float*)smem;  // buffers dead
  if (lane == 0) red[wv] = s_;
  __syncthreads();
  if (t == 0) {
    float a = 0;
#pragma unroll
    for (int i = 0; i < 8; ++i) a += red[i];
    atomicAdd(&secsum[bid & 63], a);
  }
}

// K4: loss = -( sum_j (colsum_j/B) v_j SR_j / k - sum(secsum)/(B*2k) )
__global__ __launch_bounds__(512) void k4_final(
    const float* __restrict__ colsum, const float* __restrict__ v,
    const float* __restrict__ SR, const float* __restrict__ secsum,
    const int* __restrict__ kp, float* __restrict__ out) {
  __shared__ float red[8];
  const int t = threadIdx.x;
  float cs = 0;
#pragma unroll
  for (int bk = 0; bk < 8; ++bk) cs += colsum[bk * NN + t];
  float f = (cs * (1.0f / BB)) * v[t] * SR[t];
  f = wave_reduce(f);
  if ((t & 63) == 0) red[t >> 6] = f;
  float h = 0.f;
  if (t < 64) {
    h = secsum[t];
    h = wave_reduce(h);  // wave 0: total of 64 buckets
  }
  __syncthreads();
  if (t == 0) {
    float first = 0;
#pragma unroll
    for (int i = 0; i < 8; ++i) first += red[i];
    float kk = (float)kp[0];
    float sec = h / ((float)BB * 2.0f * kk);
    out[0] = -(first / kk - sec);
  }
}

extern "C" void kernel_launch(void* const* d_in, const int* in_sizes, int n_in,
                              void* d_out, int out_size, void* d_ws, size_t ws_size,
                              hipStream_t stream) {
  const float* lsh = (const float*)d_in[0];
  const float* sig = (const float*)d_in[1];
  const float* SR = (const float*)d_in[2];
  const float* Gam = (const float*)d_in[3];
  const int* kp = (const int*)d_in[4];
  char* ws = (char*)d_ws;
  // layout: colsum 4096f | secsum 64f | v 512f | pad->32KB | Gbf 512KB | Gp 512KB | Rb 32MB
  float* colsum = (float*)ws;
  float* secsum = colsum + 4096;
  float* v = secsum + 64;
  unsigned short* Gbf = (unsigned short*)(ws + (32 << 10));
  unsigned short* Gp = (unsigned short*)(ws + (32 << 10) + (512 << 10));
  unsigned short* Rb = (unsigned short*)(ws + (32 << 10) + (1024 << 10));

  k0_prep<<<128, 256, 0, stream>>>(Gam, Gbf, colsum);
  k1_rexp<<<513, 1024, 0, stream>>>(lsh, sig, SR, Gbf, Rb, v, colsum);
  k1b_gprep<<<128, 256, 0, stream>>>(Gam, v, Gp);
  k2_gemm<<<1024, 512, 0, stream>>>(Rb, Gp, secsum);
  k4_final<<<1, 512, 0, stream>>>(colsum, v, SR, secsum, kp, (float*)d_out);
}

// Round 6
// 261.475 us; speedup vs baseline: 1.3918x; 1.3852x over previous
//
#include <hip/hip_runtime.h>
#include <hip/hip_bf16.h>
#include <stdint.h>

#define BB 32768
#define NN 512
#define CHEB_IT 10
#define NSB 16  // solver blocks

typedef __attribute__((ext_vector_type(8))) short bf16x8;
typedef __attribute__((ext_vector_type(4))) float f32x4;

__device__ __forceinline__ void gld_lds16(const void* g, void* l) {
  typedef __attribute__((address_space(1))) const unsigned int gas_u32;
  typedef __attribute__((address_space(3))) unsigned int las_u32;
  __builtin_amdgcn_global_load_lds((gas_u32*)(uintptr_t)g,
                                   (las_u32*)(uint32_t)(uintptr_t)l, 16, 0, 0);
}

__device__ __forceinline__ unsigned short f2bf(float x) {
  __hip_bfloat16 h = __float2bfloat16(x);
  return *reinterpret_cast<unsigned short*>(&h);
}

__device__ __forceinline__ float bf2f(unsigned short u) {
  return __uint_as_float(((unsigned)u) << 16);
}

__device__ __forceinline__ float wave_reduce(float v) {
#pragma unroll
  for (int off = 32; off > 0; off >>= 1) v += __shfl_xor(v, off, 64);
  return v;
}

// 16-block cooperative Chebyshev solving Gamma v = SR. Each block holds a
// 32-COLUMN slice of Gamma in LDS (Gs[512][32] bf16 = 32 KB; by symmetry these
// are the rows it owns), so per-iteration global traffic is only the 512-float
// p exchange (parity double-buffered, counter-flag sync — r3-verified protocol).
// Same constants as rounds 3-5 (passed): theta=3.16, delta=2.19, 10 iters.
__device__ void cheb_phase(const unsigned short* __restrict__ Gbf,
                           const float* __restrict__ SR, float* __restrict__ v_out,
                           float* __restrict__ pglob, unsigned int* __restrict__ ctr,
                           char* smraw) {
  unsigned short* Gs = (unsigned short*)smraw;  // [512][32]
  float* sp = (float*)(smraw + 32768);          // [512] current p
  float* red = sp + 512;                        // [16][32] partial combine
  const int t = threadIdx.x;
  const int m = blockIdx.x;  // 0..15
  // stage Gamma columns [m*32, m*32+32): 512 rows x 64 B = 32 KB, 2 calls.
  // dst ushort-off = (h*256 + (t>>2))*32 + (t&3)*8 = h*8192 + t*8 -> lane-contig.
#pragma unroll
  for (int h = 0; h < 2; ++h) {
    const int row = h * 256 + (t >> 2), sc = t & 3;
    gld_lds16(Gbf + (size_t)row * NN + m * 32 + sc * 8, Gs + row * 32 + sc * 8);
  }
  const float theta = 3.16f, delta = 2.19f;
  const float sigma1 = theta / delta;
  float rho = delta / theta;
  float x = 0.f, r = 0.f, p = 0.f;
  if (t < 32) {
    float s = SR[m * 32 + t];
    r = s;
    p = s * (1.0f / theta);
  }
  if (t < 512) sp[t] = SR[t] * (1.0f / theta);
  __syncthreads();  // barrier drains vmcnt -> Gs staged & sp visible
  for (int k = 0; k < CHEB_IT; ++k) {
    // matvec partials: thread handles columns c2,c2+1 over 8 j's
    const int c2 = (t & 15) * 2, jseg = t >> 4;
    float a0 = 0.f, a1 = 0.f;
#pragma unroll
    for (int i = 0; i < 8; ++i) {
      const int j = jseg * 8 + i;
      const unsigned g2 = *(const unsigned*)(Gs + j * 32 + c2);
      const float pv = sp[j];
      a0 += bf2f((unsigned short)(g2 & 0xffffu)) * pv;
      a1 += bf2f((unsigned short)(g2 >> 16)) * pv;
    }
    // reduce the 4 jseg-subgroups within each wave
    a0 += __shfl_xor(a0, 16, 64); a0 += __shfl_xor(a0, 32, 64);
    a1 += __shfl_xor(a1, 16, 64); a1 += __shfl_xor(a1, 32, 64);
    const int lane = t & 63, wv = t >> 6;
    if (lane < 16) {
      red[wv * 32 + lane * 2] = a0;
      red[wv * 32 + lane * 2 + 1] = a1;
    }
    __syncthreads();
    const float rho_new = 1.f / (2.f * sigma1 - rho);
    if (t < 32) {
      float ap = 0.f;
#pragma unroll
      for (int w = 0; w < 16; ++w) ap += red[w * 32 + t];
      x += p;
      r -= ap;
      p = rho_new * rho * p + (2.f * rho_new / delta) * r;
      if (k < CHEB_IT - 1)
        __hip_atomic_store(pglob + (k & 1) * 512 + m * 32 + t, p,
                           __ATOMIC_RELAXED, __HIP_MEMORY_SCOPE_AGENT);
    }
    rho = rho_new;
    if (k == CHEB_IT - 1) break;
    __threadfence();
    __syncthreads();  // all stores of this block done
    if (t == 0) {
      __hip_atomic_fetch_add(ctr, 1u, __ATOMIC_RELEASE, __HIP_MEMORY_SCOPE_AGENT);
      const unsigned tgt = (unsigned)NSB * (unsigned)(k + 1);
      int guard = 0;
      while (__hip_atomic_load(ctr, __ATOMIC_ACQUIRE, __HIP_MEMORY_SCOPE_AGENT) < tgt) {
        if (++guard > (1 << 27)) break;  // fail loud rather than hang
        __builtin_amdgcn_s_sleep(8);
      }
    }
    __syncthreads();
    if (t < 512)
      sp[t] = __hip_atomic_load(pglob + (k & 1) * 512 + t, __ATOMIC_RELAXED,
                                __HIP_MEMORY_SCOPE_AGENT);
    __syncthreads();
  }
  if (t < 32) v_out[m * 32 + t] = x;
}

// K0: Gamma -> bf16 copy; block 0 zeros colsum+secsum+v+ctr+pglob.
__global__ __launch_bounds__(256) void k0_prep(
    const float* __restrict__ Gam, unsigned short* __restrict__ Gbf,
    float* __restrict__ small_zero) {
  const int t = threadIdx.x, b = blockIdx.x;
  const size_t base = ((size_t)b * 256 + t) * 8;
  float4 g0 = *(const float4*)(Gam + base);
  float4 g1 = *(const float4*)(Gam + base + 4);
  *(ushort4*)(Gbf + base) = make_ushort4(f2bf(g0.x), f2bf(g0.y), f2bf(g0.z), f2bf(g0.w));
  *(ushort4*)(Gbf + base + 4) = make_ushort4(f2bf(g1.x), f2bf(g1.y), f2bf(g1.z), f2bf(g1.w));
  if (b == 0)
    for (int i = t; i < 5888; i += 256) small_zero[i] = 0.f;
}

// K1: blocks 0..15: LDS-resident cooperative Chebyshev -> v (hidden under
//     streaming). blocks 16..527: R = exp(sigma-lsh) -> bf16 natural [B][N]
//     (64 rows/block) + colsum buckets.
__global__ __launch_bounds__(1024) void k1_rexp(
    const float* __restrict__ lsh, const float* __restrict__ sig,
    const float* __restrict__ SR, const unsigned short* __restrict__ Gbf,
    unsigned short* __restrict__ Rb, float* __restrict__ v_out,
    float* __restrict__ colsum, float* __restrict__ pglob,
    unsigned int* __restrict__ ctr) {
  __shared__ __align__(16) char smraw[36864];  // solver 36 KB; streaming uses 16 KB
  if (blockIdx.x < NSB) {
    cheb_phase(Gbf, SR, v_out, pglob, ctr, smraw);
    return;
  }
  const int t = threadIdx.x;
  const int wb = blockIdx.x - NSB;
  const int g = t >> 7;         // row-group 0..7
  const int c = (t & 127) * 4;  // 4 owned columns
  const size_t base = (size_t)wb * 32768;  // 64 rows x 512
  float c0 = 0.f, c1 = 0.f, c2 = 0.f, c3 = 0.f;
#pragma unroll
  for (int j = 0; j < 8; ++j) {
    const size_t idx = base + (size_t)(g + 8 * j) * 512 + c;
    float4 sv = *(const float4*)(sig + idx);
    float4 lv = *(const float4*)(lsh + idx);
    float r0 = __expf(sv.x - lv.x), r1 = __expf(sv.y - lv.y);
    float r2 = __expf(sv.z - lv.z), r3 = __expf(sv.w - lv.w);
    *(ushort4*)(Rb + idx) = make_ushort4(f2bf(r0), f2bf(r1), f2bf(r2), f2bf(r3));
    c0 += r0; c1 += r1; c2 += r2; c3 += r3;
  }
  float* part = (float*)smraw;  // [8][512]
  *(float4*)(part + g * 512 + c) = make_float4(c0, c1, c2, c3);
  __syncthreads();
  if (t < 512) {
    float s = 0.f;
#pragma unroll
    for (int gg = 0; gg < 8; ++gg) s += part[gg * 512 + t];
    atomicAdd(&colsum[(wb & 7) * NN + t], s);
  }
}

// K1b: Gp = bf16( diag(v) * Gamma * diag(v) )  (symmetric since Gamma is).
__global__ __launch_bounds__(256) void k1b_gprep(
    const float* __restrict__ Gam, const float* __restrict__ v,
    unsigned short* __restrict__ Gp) {
  const int t = threadIdx.x;
  const size_t e = ((size_t)blockIdx.x * 256 + t) * 8;
  const int i = (int)(e >> 9), j = (int)(e & 511);
  const float vi = v[i];
  float4 va = *(const float4*)(v + j);
  float4 vb = *(const float4*)(v + j + 4);
  float4 g0 = *(const float4*)(Gam + e);
  float4 g1 = *(const float4*)(Gam + e + 4);
  *(ushort4*)(Gp + e) = make_ushort4(f2bf(g0.x * vi * va.x), f2bf(g0.y * vi * va.y),
                                     f2bf(g0.z * vi * va.z), f2bf(g0.w * vi * va.w));
  *(ushort4*)(Gp + e + 4) = make_ushort4(f2bf(g1.x * vi * vb.x), f2bf(g1.y * vi * vb.y),
                                         f2bf(g1.z * vi * vb.z), f2bf(g1.w * vi * vb.w));
}

// K2: GEMM T = R * Gp (BM=256, BN=256, BK=32, K=512), fused contraction
//     secsum[bid&63] += sum_{b,n} T[b][n] * R[b][n].
//     8 waves @ 128x64 wave-tile (acc[8][4]); double-buffered 64 KB LDS;
//     4x higher arithmetic intensity per staged byte than the 128^2 version
//     (per-CU pull is the suspected limiter). XCD mapping: the 2 n-halves of
//     a b-slice are consecutive within an XCD's chunk.
__global__ __launch_bounds__(512) void k2_gemm(
    const unsigned short* __restrict__ Rb, const unsigned short* __restrict__ Gp,
    float* __restrict__ secsum) {
  __shared__ __align__(16) unsigned short smem[32768];  // 2 x (As[256][32] | Bs[256][32])
  const int bid = blockIdx.x;
  const int xcd = bid & 7, ixc = bid >> 3;       // 32 blocks per XCD chunk
  const int nt_ = ixc & 1;
  const int bs_ = xcd * 16 + (ixc >> 1);         // 0..127
  const int b0 = bs_ * 256;
  const int n0 = nt_ * 256;
  const int t = threadIdx.x, lane = t & 63, wv = t >> 6;
  const int wr = wv >> 2, wc = wv & 3;           // 2x4 waves
  const int lm = lane & 15, lq = lane >> 4;
  const int srow = t >> 2, sc = t & 3;           // staging role: 128 rows/call
  f32x4 acc[8][4];
#pragma unroll
  for (int a = 0; a < 8; ++a)
#pragma unroll
    for (int b = 0; b < 4; ++b) acc[a][b] = (f32x4){0.f, 0.f, 0.f, 0.f};

  // swizzled source chunk (4-slot XOR involution on row&3)
#define STAGE(kk, buf)                                                              \
  {                                                                                 \
    unsigned short* As_ = smem + (buf)*16384;                                       \
    unsigned short* Bs_ = As_ + 8192;                                               \
    const int scol_ = (sc ^ (srow & 3)) * 8;                                        \
    gld_lds16(Rb + (size_t)(b0 + srow) * NN + (kk) + scol_, As_ + srow * 32 + sc * 8); \
    gld_lds16(Rb + (size_t)(b0 + 128 + srow) * NN + (kk) + scol_,                   \
              As_ + (128 + srow) * 32 + sc * 8);                                    \
    gld_lds16(Gp + (size_t)(n0 + srow) * NN + (kk) + scol_, Bs_ + srow * 32 + sc * 8); \
    gld_lds16(Gp + (size_t)(n0 + 128 + srow) * NN + (kk) + scol_,                   \
              Bs_ + (128 + srow) * 32 + sc * 8);                                    \
  }

  STAGE(0, 0);
  __syncthreads();
  for (int c = 0; c < 16; ++c) {
    if (c < 15) STAGE((c + 1) * 32, (c + 1) & 1);  // in flight during compute
    const unsigned short* As = smem + (c & 1) * 16384;
    const unsigned short* Bs = As + 8192;
    bf16x8 af[8], bfr[4];
#pragma unroll
    for (int g = 0; g < 8; ++g) {
      const int row = wr * 128 + g * 16 + lm;
      af[g] = *(const bf16x8*)(As + row * 32 + ((lq ^ (row & 3))) * 8);
    }
#pragma unroll
    for (int g = 0; g < 4; ++g) {
      const int row = wc * 64 + g * 16 + lm;
      bfr[g] = *(const bf16x8*)(Bs + row * 32 + ((lq ^ (row & 3))) * 8);
    }
#pragma unroll
    for (int gm = 0; gm < 8; ++gm)
#pragma unroll
      for (int gn = 0; gn < 4; ++gn)
        acc[gm][gn] = __builtin_amdgcn_mfma_f32_16x16x32_bf16(af[gm], bfr[gn], acc[gm][gn], 0, 0, 0);
    __syncthreads();  // drains vmcnt: next buffer ready; cur safe to overwrite
  }
#undef STAGE

  // epilogue: s = sum_{frag} acc * R[b][n]  (C/D: col=lane&15, row=(lane>>4)*4+reg)
  float s_ = 0.f;
#pragma unroll
  for (int gm = 0; gm < 8; ++gm) {
    const int rb = b0 + wr * 128 + gm * 16 + lq * 4;
#pragma unroll
    for (int gn = 0; gn < 4; ++gn) {
      const int cl = n0 + wc * 64 + gn * 16 + lm;
      const unsigned short* rp = Rb + (size_t)rb * NN + cl;
      s_ += acc[gm][gn][0] * bf2f(rp[0]);
      s_ += acc[gm][gn][1] * bf2f(rp[NN]);
      s_ += acc[gm][gn][2] * bf2f(rp[2 * NN]);
      s_ += acc[gm][gn][3] * bf2f(rp[3 * NN]);
    }
  }
  s_ = wave_reduce(s_);
  float* red = (float*)smem;  // buffers dead
  if (lane == 0) red[wv] = s_;
  __syncthreads();
  if (t == 0) {
    float a = 0;
#pragma unroll
    for (int i = 0; i < 8; ++i) a += red[i];
    atomicAdd(&secsum[bid & 63], a);
  }
}

// K4: loss = -( sum_j (colsum_j/B) v_j SR_j / k - sum(secsum)/(B*2k) )
__global__ __launch_bounds__(512) void k4_final(
    const float* __restrict__ colsum, const float* __restrict__ v,
    const float* __restrict__ SR, const float* __restrict__ secsum,
    const int* __restrict__ kp, float* __restrict__ out) {
  __shared__ float red[8];
  const int t = threadIdx.x;
  float cs = 0;
#pragma unroll
  for (int bk = 0; bk < 8; ++bk) cs += colsum[bk * NN + t];
  float f = (cs * (1.0f / BB)) * v[t] * SR[t];
  f = wave_reduce(f);
  if ((t & 63) == 0) red[t >> 6] = f;
  float h = 0.f;
  if (t < 64) {
    h = secsum[t];
    h = wave_reduce(h);  // wave 0: total of 64 buckets
  }
  __syncthreads();
  if (t == 0) {
    float first = 0;
#pragma unroll
    for (int i = 0; i < 8; ++i) first += red[i];
    float kk = (float)kp[0];
    float sec = h / ((float)BB * 2.0f * kk);
    out[0] = -(first / kk - sec);
  }
}

extern "C" void kernel_launch(void* const* d_in, const int* in_sizes, int n_in,
                              void* d_out, int out_size, void* d_ws, size_t ws_size,
                              hipStream_t stream) {
  const float* lsh = (const float*)d_in[0];
  const float* sig = (const float*)d_in[1];
  const float* SR = (const float*)d_in[2];
  const float* Gam = (const float*)d_in[3];
  const int* kp = (const int*)d_in[4];
  char* ws = (char*)d_ws;
  // layout: colsum 4096f | secsum 64f | v 512f | ctr 16u | pglob 1024f | pad->32KB
  //         | Gbf 512KB | Gp 512KB | Rb 32MB
  float* colsum = (float*)ws;
  float* secsum = colsum + 4096;
  float* v = secsum + 64;
  unsigned int* ctr = (unsigned int*)(v + 512);
  float* pglob = (float*)(ctr + 16);
  unsigned short* Gbf = (unsigned short*)(ws + (32 << 10));
  unsigned short* Gp = (unsigned short*)(ws + (32 << 10) + (512 << 10));
  unsigned short* Rb = (unsigned short*)(ws + (32 << 10) + (1024 << 10));

  k0_prep<<<128, 256, 0, stream>>>(Gam, Gbf, colsum);
  k1_rexp<<<NSB + 512, 1024, 0, stream>>>(lsh, sig, SR, Gbf, Rb, v, colsum, pglob, ctr);
  k1b_gprep<<<128, 256, 0, stream>>>(Gam, v, Gp);
  k2_gemm<<<256, 512, 0, stream>>>(Rb, Gp, secsum);
  k4_final<<<1, 512, 0, stream>>>(colsum, v, SR, secsum, kp, (float*)d_out);
}

// Round 7
// 232.905 us; speedup vs baseline: 1.5625x; 1.1227x over previous
//
#include <hip/hip_runtime.h>
#include <hip/hip_bf16.h>
#include <stdint.h>

#define BB 32768
#define NN 512
#define CHEB_IT 10
#define NSB 16    // solver blocks (first 16 of k2 launch)
#define NTILE 10  // upper-triangle 128x128 tiles of 512x512
#define NPART 64  // K-parts of 512 b's each

typedef __attribute__((ext_vector_type(8))) short bf16x8;
typedef __attribute__((ext_vector_type(4))) float f32x4;

__device__ __forceinline__ void gld_lds16(const void* g, void* l) {
  typedef __attribute__((address_space(1))) const unsigned int gas_u32;
  typedef __attribute__((address_space(3))) unsigned int las_u32;
  __builtin_amdgcn_global_load_lds((gas_u32*)(uintptr_t)g,
                                   (las_u32*)(uint32_t)(uintptr_t)l, 16, 0, 0);
}

__device__ __forceinline__ unsigned short f2bf(float x) {
  __hip_bfloat16 h = __float2bfloat16(x);
  return *reinterpret_cast<unsigned short*>(&h);
}

__device__ __forceinline__ float bf2f(unsigned short u) {
  return __uint_as_float(((unsigned)u) << 16);
}

__device__ __forceinline__ float wave_reduce(float v) {
#pragma unroll
  for (int off = 32; off > 0; off >>= 1) v += __shfl_xor(v, off, 64);
  return v;
}

// 16-block cooperative Chebyshev solving Gamma v = SR (512 threads/block).
// Runs CONCURRENTLY with the SYRK blocks of k2 (v is consumed only by k3).
// Each block holds 32 Gamma columns in LDS (32 KB); per-iteration global
// traffic is only the 512-float p exchange (r6-verified protocol, passed).
// Constants theta=3.16, delta=2.19 verified passing rounds 3-6.
__device__ void cheb_phase(const unsigned short* __restrict__ Gbf,
                           const float* __restrict__ SR, float* __restrict__ v_out,
                           float* __restrict__ pglob, unsigned int* __restrict__ ctr,
                           char* smraw) {
  unsigned short* Gs = (unsigned short*)smraw;  // [512][32]
  float* sp = (float*)(smraw + 32768);          // [512] current p
  float* red = sp + 512;                        // [8][32] partial combine
  const int t = threadIdx.x;
  const int m = blockIdx.x;  // 0..15
  // stage Gamma columns [m*32, m*32+32): 4 calls x 128 rows (lane-linear dst)
#pragma unroll
  for (int h = 0; h < 4; ++h) {
    const int row = h * 128 + (t >> 2), sc = t & 3;
    gld_lds16(Gbf + (size_t)row * NN + m * 32 + sc * 8, Gs + row * 32 + sc * 8);
  }
  const float theta = 3.16f, delta = 2.19f;
  const float sigma1 = theta / delta;
  float rho = delta / theta;
  float x = 0.f, r = 0.f, p = 0.f;
  if (t < 32) {
    float s = SR[m * 32 + t];
    r = s;
    p = s * (1.0f / theta);
  }
  sp[t] = SR[t] * (1.0f / theta);
  __syncthreads();  // barrier drains vmcnt -> Gs staged & sp visible
  for (int k = 0; k < CHEB_IT; ++k) {
    // matvec partials: thread handles col-pair c2 over 16 j's
    const int c2 = (t & 15) * 2, jseg = t >> 4;  // jseg 0..31
    float a0 = 0.f, a1 = 0.f;
#pragma unroll
    for (int i = 0; i < 16; ++i) {
      const int j = jseg * 16 + i;
      const unsigned g2 = *(const unsigned*)(Gs + j * 32 + c2);
      const float pv = sp[j];
      a0 += bf2f((unsigned short)(g2 & 0xffffu)) * pv;
      a1 += bf2f((unsigned short)(g2 >> 16)) * pv;
    }
    a0 += __shfl_xor(a0, 16, 64); a0 += __shfl_xor(a0, 32, 64);
    a1 += __shfl_xor(a1, 16, 64); a1 += __shfl_xor(a1, 32, 64);
    const int lane = t & 63, wv = t >> 6;
    if (lane < 16) {
      red[wv * 32 + lane * 2] = a0;
      red[wv * 32 + lane * 2 + 1] = a1;
    }
    __syncthreads();
    const float rho_new = 1.f / (2.f * sigma1 - rho);
    if (t < 32) {
      float ap = 0.f;
#pragma unroll
      for (int w = 0; w < 8; ++w) ap += red[w * 32 + t];
      x += p;
      r -= ap;
      p = rho_new * rho * p + (2.f * rho_new / delta) * r;
      if (k < CHEB_IT - 1)
        __hip_atomic_store(pglob + (k & 1) * 512 + m * 32 + t, p,
                           __ATOMIC_RELAXED, __HIP_MEMORY_SCOPE_AGENT);
    }
    rho = rho_new;
    if (k == CHEB_IT - 1) break;
    __threadfence();
    __syncthreads();
    if (t == 0) {
      __hip_atomic_fetch_add(ctr, 1u, __ATOMIC_RELEASE, __HIP_MEMORY_SCOPE_AGENT);
      const unsigned tgt = (unsigned)NSB * (unsigned)(k + 1);
      int guard = 0;
      while (__hip_atomic_load(ctr, __ATOMIC_ACQUIRE, __HIP_MEMORY_SCOPE_AGENT) < tgt) {
        if (++guard > (1 << 27)) break;  // fail loud rather than hang
        __builtin_amdgcn_s_sleep(8);
      }
    }
    __syncthreads();
    sp[t] = __hip_atomic_load(pglob + (k & 1) * 512 + t, __ATOMIC_RELAXED,
                              __HIP_MEMORY_SCOPE_AGENT);
    __syncthreads();
  }
  if (t < 32) v_out[m * 32 + t] = x;
}

// K0: Gamma -> bf16 copy; block 0 zeros colsum+secsum+v+ctr+pglob.
__global__ __launch_bounds__(256) void k0_prep(
    const float* __restrict__ Gam, unsigned short* __restrict__ Gbf,
    float* __restrict__ small_zero) {
  const int t = threadIdx.x, b = blockIdx.x;
  const size_t base = ((size_t)b * 256 + t) * 8;
  float4 g0 = *(const float4*)(Gam + base);
  float4 g1 = *(const float4*)(Gam + base + 4);
  *(ushort4*)(Gbf + base) = make_ushort4(f2bf(g0.x), f2bf(g0.y), f2bf(g0.z), f2bf(g0.w));
  *(ushort4*)(Gbf + base + 4) = make_ushort4(f2bf(g1.x), f2bf(g1.y), f2bf(g1.z), f2bf(g1.w));
  if (b == 0)
    for (int i = t; i < 5888; i += 256) small_zero[i] = 0.f;
}

// K1: pure streaming: R = exp(sigma-lsh) -> bf16 TRANSPOSED Rt[N][B]
//     (LDS-tiled transpose, r1-verified) + colsum via parallel LDS reduce.
//     512 blocks x 512 threads, 64 b-rows per block. No solver inside.
#define TSTRIDE 132
__global__ __launch_bounds__(512) void k1_rt(
    const float* __restrict__ lsh, const float* __restrict__ sig,
    unsigned short* __restrict__ Rt, float* __restrict__ colsum) {
  __shared__ __align__(16) float sm[4736];  // tile [64][132] ushorts + redc[512]
  unsigned short* tile = (unsigned short*)sm;
  float* redc = sm + 4224;
  const int t = threadIdx.x;
  const int r = t >> 3, cg = t & 7;   // load: row r, 16 consecutive cols
  const int jr = t >> 3, cc = t & 7;  // readout: j row, b-chunk
  const size_t bb = (size_t)blockIdx.x * 64;
  for (int jt = 0; jt < 4; ++jt) {
    const int j0 = jt * 128;
    const size_t off = (bb + r) * NN + j0 + cg * 16;
    float4 s0 = *(const float4*)(sig + off);
    float4 s1 = *(const float4*)(sig + off + 4);
    float4 s2 = *(const float4*)(sig + off + 8);
    float4 s3 = *(const float4*)(sig + off + 12);
    float4 l0 = *(const float4*)(lsh + off);
    float4 l1 = *(const float4*)(lsh + off + 4);
    float4 l2 = *(const float4*)(lsh + off + 8);
    float4 l3 = *(const float4*)(lsh + off + 12);
    ushort4 w0 = make_ushort4(f2bf(__expf(s0.x - l0.x)), f2bf(__expf(s0.y - l0.y)),
                              f2bf(__expf(s0.z - l0.z)), f2bf(__expf(s0.w - l0.w)));
    ushort4 w1 = make_ushort4(f2bf(__expf(s1.x - l1.x)), f2bf(__expf(s1.y - l1.y)),
                              f2bf(__expf(s1.z - l1.z)), f2bf(__expf(s1.w - l1.w)));
    ushort4 w2 = make_ushort4(f2bf(__expf(s2.x - l2.x)), f2bf(__expf(s2.y - l2.y)),
                              f2bf(__expf(s2.z - l2.z)), f2bf(__expf(s2.w - l2.w)));
    ushort4 w3 = make_ushort4(f2bf(__expf(s3.x - l3.x)), f2bf(__expf(s3.y - l3.y)),
                              f2bf(__expf(s3.z - l3.z)), f2bf(__expf(s3.w - l3.w)));
    if (jt) __syncthreads();
    *(ushort4*)(&tile[r * TSTRIDE + cg * 16 + 0]) = w0;
    *(ushort4*)(&tile[r * TSTRIDE + cg * 16 + 4]) = w1;
    *(ushort4*)(&tile[r * TSTRIDE + cg * 16 + 8]) = w2;
    *(ushort4*)(&tile[r * TSTRIDE + cg * 16 + 12]) = w3;
    __syncthreads();
#pragma unroll
    for (int pass = 0; pass < 2; ++pass) {
      const int j = jr + pass * 64;
      unsigned int u[4];
      float csum = 0.f;
#pragma unroll
      for (int q = 0; q < 4; ++q) {
        unsigned int lo = tile[(cc * 8 + 2 * q) * TSTRIDE + j];
        unsigned int hi = tile[(cc * 8 + 2 * q + 1) * TSTRIDE + j];
        u[q] = lo | (hi << 16);
        csum += bf2f((unsigned short)lo) + bf2f((unsigned short)hi);
      }
      *(uint4*)(Rt + (size_t)(j0 + j) * BB + bb + cc * 8) =
          make_uint4(u[0], u[1], u[2], u[3]);
      redc[t] = csum;
      __syncthreads();
      if (t < 64) {
        float s = 0.f;
#pragma unroll
        for (int q = 0; q < 8; ++q) s += redc[t * 8 + q];
        atomicAdd(&colsum[(blockIdx.x & 7) * NN + j0 + pass * 64 + t], s);
      }
      __syncthreads();
    }
  }
}

// K2: blocks 0..15: Chebyshev solver -> v (concurrent, hidden).
//     blocks 16..655: SYRK Cpart[kc] = Rt_i * Rt_j^T over 512-b K-chunk,
//     upper-triangle tiles, dbuf LDS + issue-early gld_lds + swizzle
//     (r3-verified GEMM core with operands = Rt rows).
__global__ __launch_bounds__(512) void k2_syrk(
    const unsigned short* __restrict__ Rt, const unsigned short* __restrict__ Gbf,
    const float* __restrict__ SR, unsigned short* __restrict__ Cpart,
    float* __restrict__ v_out, float* __restrict__ pglob,
    unsigned int* __restrict__ ctr) {
  __shared__ __align__(16) char smraw[65536];
  if (blockIdx.x < NSB) {
    cheb_phase(Gbf, SR, v_out, pglob, ctr, smraw);
    return;
  }
  unsigned short* smem = (unsigned short*)smraw;
  const int wb = blockIdx.x - NSB;
  const int kc = wb / NTILE, tt = wb % NTILE;
  const int ti = (int)((0x3221110000ULL >> (4 * tt)) & 0xF);
  const int tj = (int)((0x3323213210ULL >> (4 * tt)) & 0xF);
  const int i0 = ti * 128, j0 = tj * 128;
  const int diag = (ti == tj);
  const size_t b0 = (size_t)kc * 512;
  const int t = threadIdx.x, lane = t & 63, wv = t >> 6;
  const int wi = (wv & 3) * 32, wj = (wv >> 2) * 64;
  const int lm = lane & 15, lq = lane >> 4;
  const int xr = lm & 7;
  const int srow = t >> 3, sc = t & 7;
  const int scol = (sc ^ (srow & 7)) * 8;  // pre-swizzled source chunk (involution)
  f32x4 acc[2][4];
#pragma unroll
  for (int a = 0; a < 2; ++a)
#pragma unroll
    for (int b = 0; b < 4; ++b) acc[a][b] = (f32x4){0.f, 0.f, 0.f, 0.f};

#define STAGE(kk, buf)                                                              \
  {                                                                                 \
    unsigned short* As_ = smem + (buf)*16384;                                       \
    unsigned short* Bs_ = diag ? As_ : As_ + 8192;                                  \
    gld_lds16(Rt + (size_t)(i0 + srow) * BB + b0 + (kk) + scol,                     \
              As_ + srow * 64 + sc * 8);                                            \
    gld_lds16(Rt + (size_t)(i0 + 64 + srow) * BB + b0 + (kk) + scol,                \
              As_ + (64 + srow) * 64 + sc * 8);                                     \
    if (!diag) {                                                                    \
      gld_lds16(Rt + (size_t)(j0 + srow) * BB + b0 + (kk) + scol,                   \
                Bs_ + srow * 64 + sc * 8);                                          \
      gld_lds16(Rt + (size_t)(j0 + 64 + srow) * BB + b0 + (kk) + scol,              \
                Bs_ + (64 + srow) * 64 + sc * 8);                                   \
    }                                                                               \
  }

  STAGE(0, 0);
  __syncthreads();
  for (int c = 0; c < 8; ++c) {
    if (c < 7) STAGE((c + 1) * 64, (c + 1) & 1);  // in flight during compute
    const unsigned short* As = smem + (c & 1) * 16384;
    const unsigned short* Bs = diag ? As : As + 8192;
#pragma unroll
    for (int s = 0; s < 2; ++s) {
      bf16x8 af[2], bfr[4];
#pragma unroll
      for (int g = 0; g < 2; ++g)
        af[g] = *(const bf16x8*)(As + (wi + g * 16 + lm) * 64 + ((s * 4 + lq) ^ xr) * 8);
#pragma unroll
      for (int g = 0; g < 4; ++g)
        bfr[g] = *(const bf16x8*)(Bs + (wj + g * 16 + lm) * 64 + ((s * 4 + lq) ^ xr) * 8);
#pragma unroll
      for (int gm = 0; gm < 2; ++gm)
#pragma unroll
        for (int gn = 0; gn < 4; ++gn)
          acc[gm][gn] = __builtin_amdgcn_mfma_f32_16x16x32_bf16(af[gm], bfr[gn], acc[gm][gn], 0, 0, 0);
    }
    __syncthreads();  // drains vmcnt: next buffer ready; cur safe to overwrite
  }
#undef STAGE

  // epilogue: write upper-triangle Cpart only (k3 applies weight 2 off-diag)
  unsigned short* Cw = Cpart + (size_t)kc * NN * NN;
#pragma unroll
  for (int gm = 0; gm < 2; ++gm) {
    const int rbase = i0 + wi + gm * 16 + lq * 4;
#pragma unroll
    for (int gn = 0; gn < 4; ++gn) {
      const int col = j0 + wj + gn * 16 + lm;
      Cw[(size_t)(rbase + 0) * NN + col] = f2bf(acc[gm][gn][0]);
      Cw[(size_t)(rbase + 1) * NN + col] = f2bf(acc[gm][gn][1]);
      Cw[(size_t)(rbase + 2) * NN + col] = f2bf(acc[gm][gn][2]);
      Cw[(size_t)(rbase + 3) * NN + col] = f2bf(acc[gm][gn][3]);
    }
  }
}

// K3: secondsum = sum over upper-tri tiles of w * v_i Gamma_ij C_ij v_j,
//     w = 1 (diag tile) or 2 (off-diag). 160 blocks x 256 threads.
__global__ __launch_bounds__(256) void k3_contract(
    const float* __restrict__ Gamma, const unsigned short* __restrict__ Cpart,
    const float* __restrict__ v, float* __restrict__ secondsum) {
  __shared__ float red[4];
  const int t = threadIdx.x;
  const int tidx = blockIdx.x >> 4;                 // tile 0..9
  const int sub = ((blockIdx.x & 15) << 10) + t * 4;  // 0..16383 within tile
  const int ti = (int)((0x3221110000ULL >> (4 * tidx)) & 0xF);
  const int tj = (int)((0x3323213210ULL >> (4 * tidx)) & 0xF);
  const float w = (ti == tj) ? 1.f : 2.f;
  const int i = ti * 128 + (sub >> 7);
  const int j = tj * 128 + (sub & 127);
  const size_t e = (size_t)i * NN + j;
  float cx = 0, cy = 0, cz = 0, cw = 0;
  for (int pp = 0; pp < NPART; ++pp) {
    ushort4 u = *(const ushort4*)(Cpart + (size_t)pp * NN * NN + e);
    cx += bf2f(u.x); cy += bf2f(u.y); cz += bf2f(u.z); cw += bf2f(u.w);
  }
  float4 g = *(const float4*)(Gamma + e);
  float4 vj = *(const float4*)(v + j);
  float vi = v[i];
  float p = w * vi * (g.x * cx * vj.x + g.y * cy * vj.y + g.z * cz * vj.z + g.w * cw * vj.w);
  p = wave_reduce(p);
  if ((t & 63) == 0) red[t >> 6] = p;
  __syncthreads();
  if (t == 0) atomicAdd(secondsum, red[0] + red[1] + red[2] + red[3]);
}

// K4: loss = -( sum_j (colsum_j/B) v_j SR_j / k - secondsum/(B*2k) )
__global__ __launch_bounds__(512) void k4_final(
    const float* __restrict__ colsum, const float* __restrict__ v,
    const float* __restrict__ SR, const float* __restrict__ secondsum,
    const int* __restrict__ kp, float* __restrict__ out) {
  __shared__ float red[8];
  const int t = threadIdx.x;
  float cs = 0;
#pragma unroll
  for (int bk = 0; bk < 8; ++bk) cs += colsum[bk * NN + t];
  float f = (cs * (1.0f / BB)) * v[t] * SR[t];
  f = wave_reduce(f);
  if ((t & 63) == 0) red[t >> 6] = f;
  __syncthreads();
  if (t == 0) {
    float first = 0;
#pragma unroll
    for (int i = 0; i < 8; ++i) first += red[i];
    float kk = (float)kp[0];
    float sec = secondsum[0] / ((float)BB * 2.0f * kk);
    out[0] = -(first / kk - sec);
  }
}

extern "C" void kernel_launch(void* const* d_in, const int* in_sizes, int n_in,
                              void* d_out, int out_size, void* d_ws, size_t ws_size,
                              hipStream_t stream) {
  const float* lsh = (const float*)d_in[0];
  const float* sig = (const float*)d_in[1];
  const float* SR = (const float*)d_in[2];
  const float* Gam = (const float*)d_in[3];
  const int* kp = (const int*)d_in[4];
  char* ws = (char*)d_ws;
  // layout: Cpart 32MB | colsum 4096f secsum 64f v 512f ctr 16u pglob 1024f | Gbf 512KB | Rt 32MB
  unsigned short* Cpart = (unsigned short*)ws;
  const size_t coff = (size_t)NPART * NN * NN * sizeof(unsigned short);  // 32 MB
  float* colsum = (float*)(ws + coff);
  float* secsum = colsum + 4096;
  float* v = secsum + 64;
  unsigned int* ctr = (unsigned int*)(v + 512);
  float* pglob = (float*)(ctr + 16);
  unsigned short* Gbf = (unsigned short*)(ws + coff + (32 << 10));
  unsigned short* Rt = (unsigned short*)(ws + coff + (32 << 10) + (512 << 10));

  k0_prep<<<128, 256, 0, stream>>>(Gam, Gbf, colsum);
  k1_rt<<<512, 512, 0, stream>>>(lsh, sig, Rt, colsum);
  k2_syrk<<<NSB + NPART * NTILE, 512, 0, stream>>>(Rt, Gbf, SR, Cpart, v, pglob, ctr);
  k3_contract<<<160, 256, 0, stream>>>(Gam, Cpart, v, secsum);
  k4_final<<<1, 512, 0, stream>>>(colsum, v, SR, secsum, kp, (float*)d_out);
}